// Round 14
// baseline (28.811 us; speedup 1.0000x reference)
//
#include <hip/hip_runtime.h>
#include <cstdint>

// Rule 30, 2 states, r=1, wrap. idx = L + 2C + 4R, table = bits of 30
// reduces to: new = R ^ (C | L).
//
// B=16 rows, W=2048 cells, T=1024 steps, history = T+1 states.
// Output: int32 [B][T+1][W] (reference returns uint8 -> harness int32).
//
// Round-14 = round-12 (best, 27.4us) + COHORT DE-SYNCHRONIZATION.
//   R12's blk->(b,r) map put the SAME r on all 4 co-resident blocks of a
//   CU (consecutive blk share r): their equal-length chains finish
//   simultaneously -> per-CU store stream has a ~2.2us dead phase, then a
//   burst. Duty cycle ~= store/(chain+store) predicts the measured ~19 of
//   26 GB/s/CU share. R13 (1 block/CU) had the same flaw via its shared
//   barrier. Fix: bijective relabel so any co-resident cohort (contiguous
//   blk OR stride-256 XCD round-robin) spans r >= 16 apart:
//     r = rev6((blk ^ (blk>>8)) & 63), b = (blk>>6) & 15.
//   Chains then complete staggered ~1.1us apart; every CU always has a
//   block mid-store. Everything else identical to R12.
//
// Structure (R8/R12, proven): 1024 blocks x 256 thr. Wave 0 re-runs row
// b's bit-packed chain from t=0 (ghost-zone window: one 32-bit shuffle
// pair per 16 steps; rule on the 64-bit window is
// win = (win>>1) ^ (win | (win<<1)); middle 32 bits valid 16 steps),
// parks its 16-state chunk in LDS; barrier; all 4 waves expand 4 states
// each as contiguous plain int4 wave-stores.

#define B 16
#define W 2048
#define T_ITERS 1024
#define HIST (T_ITERS + 1)
#define LANES 64
#define K_STEPS 16
#define RBLKS (T_ITERS / K_STEPS)      // 64 chunks
#define ROW_I4 (W / 4)                 // 512 int4 per state row

typedef unsigned long long u64;
typedef int v4i __attribute__((ext_vector_type(4)));

__device__ __forceinline__ void store_nib(v4i* o, unsigned nib) {
    v4i f;
    f.x = (int)(nib & 1u);
    f.y = (int)((nib >> 1) & 1u);
    f.z = (int)((nib >> 2) & 1u);
    f.w = (int)((nib >> 3) & 1u);
    *o = f;                              // plain global_store_dwordx4
}

__global__ __launch_bounds__(256) void ca_redundant(const float* __restrict__ x,
                                                    v4i* __restrict__ out) {
    __shared__ unsigned st[K_STEPS][LANES];   // chunk's 16 packed states
    __shared__ unsigned st0[LANES];           // packed t=0 (r==0 only)

    const int blk = blockIdx.x;
    // cohort-desync mapping: co-resident blocks get r spread >= 16
    const int z = (blk ^ (blk >> 8)) & 63;
    const int r = ((z & 1) << 5) | ((z & 2) << 3) | ((z & 4) << 1) |
                  ((z & 8) >> 1) | ((z & 16) >> 3) | ((z & 32) >> 5);  // rev6
    const int b = (blk >> 6) & (B - 1);       // row
    const int tid = threadIdx.x;
    const int wave = tid >> 6;                // 0..3
    const int l = tid & 63;                   // lane

    if (wave == 0) {
        // ---- pack 32 thresholded floats into a u32 (bit i = cell 32l+i) ----
        const float4* xv = (const float4*)(x + (size_t)b * W + (size_t)l * 32);
        unsigned m = 0;
        #pragma unroll
        for (int i = 0; i < 8; ++i) {
            float4 v = xv[i];
            unsigned n = (v.x >= 0.5f ? 1u : 0u) | (v.y >= 0.5f ? 2u : 0u) |
                         (v.z >= 0.5f ? 4u : 0u) | (v.w >= 0.5f ? 8u : 0u);
            m |= n << (4 * i);
        }
        if (r == 0) st0[l] = m;

        // ---- chain: r+1 exchange groups of 16 steps; save only group r ----
        for (int g = 0; g <= r; ++g) {
            unsigned left  = __shfl(m, (l + LANES - 1) & (LANES - 1));
            unsigned right = __shfl(m, (l + 1) & (LANES - 1));
            // window bit p = cell (32l - 16 + p); bits [16..47] = own cells
            u64 win = ((u64)(left >> 16)) | ((u64)m << 16) | ((u64)right << 48);
            if (g < r) {
                #pragma unroll
                for (int j = 0; j < K_STEPS; ++j)
                    win = (win >> 1) ^ (win | (win << 1));   // rule 30, 64 bits
                m = (unsigned)(win >> 16);                   // valid at 16 steps
            } else {
                #pragma unroll
                for (int j = 0; j < K_STEPS; ++j) {
                    win = (win >> 1) ^ (win | (win << 1));
                    m = (unsigned)(win >> 16);               // valid for j<=15
                    st[j][l] = m;                            // 2 lanes/bank: free
                }
            }
        }
    }
    __syncthreads();

    // ---- expand: all 4 waves, 4 states each; contiguous int4 stores ----
    // nibble c of a packed row: word c>>3 = (l>>3)+8i, shift (l&7)*4.
    // LDS reads: 8-lane broadcast per word, 8 words across 8 banks -> clean.
    if (r == 0) {
        // t = 0 row: 512 int4 split across all 256 threads (2 each)
        v4i* o = out + ((size_t)b * HIST) * ROW_I4;
        #pragma unroll
        for (int h = 0; h < 2; ++h) {
            int c = tid + 256 * h;
            unsigned u = st0[c >> 3];
            store_nib(o + c, (u >> ((c & 7) * 4)) & 0xFu);
        }
    }
    #pragma unroll
    for (int jj = 0; jj < 4; ++jj) {
        const int j = wave * 4 + jj;
        v4i* o = out + ((size_t)b * HIST + (size_t)(r * K_STEPS + 1 + j)) * ROW_I4;
        #pragma unroll
        for (int i = 0; i < 8; ++i) {
            unsigned u = st[j][(l >> 3) + 8 * i];
            store_nib(o + l + 64 * i, (u >> ((l & 7) * 4)) & 0xFu);
        }
    }
}

extern "C" void kernel_launch(void* const* d_in, const int* in_sizes, int n_in,
                              void* d_out, int out_size, void* d_ws, size_t ws_size,
                              hipStream_t stream) {
    const float* x = (const float*)d_in[0];
    // 1024 independent blocks (4 waves each); no workspace needed.
    ca_redundant<<<B * RBLKS, 256, 0, stream>>>(x, (v4i*)d_out);
}

// Round 15
// 27.426 us; speedup vs baseline: 1.0505x; 1.0505x over previous
//
#include <hip/hip_runtime.h>
#include <cstdint>

// Rule 30, 2 states, r=1, wrap. idx = L + 2C + 4R, table = bits of 30
// reduces to: new = R ^ (C | L).
//
// B=16 rows, W=2048 cells, T=1024 steps, history = T+1 states.
// Output: int32 [B][T+1][W] (reference returns uint8 -> harness int32).
//
// Round-15 = round-12 (best, 27.4us) + REGISTER-STAGED STORE BURSTS.
//   Scheduling levers exhausted (R8-R14 all 27-31us): NT/plain, waves/CU,
//   stream length, head length, cohort desync. Last mechanistic theory:
//   our store stream interleaves each 16B store with a ds_read + ~6 VALU
//   (the fill kernel that hits 6.7 TB/s issues pure back-to-back stores).
//   Fix at FIXED structure: per wave, expand 2 states fully into 64 data
//   VGPRs (16 ds_read_b32 + VALU), then fire 16 back-to-back
//   global_store_dwordx4 covering 16KB contiguous (rows t=j,j+1 adjacent).
//   If flat -> declare roofline: 134.4MB mandatory HBM traffic at the
//   demonstrated 6.4-6.9 TB/s (20.3-21us) + ~2us ramp + harness fill-drain
//   interference = ~26-28us platform floor.
//
// Structure (R12, proven): 1024 blocks = 16 rows x 64 chunks, 256 thr.
// Wave 0 re-runs row b's bit-packed chain from t=0 (ghost-zone window:
// one 32-bit shuffle pair per 16 steps; rule on the 64-bit window is
// win = (win>>1) ^ (win | (win<<1)); middle 32 bits valid 16 steps),
// parks its 16-state chunk in LDS; barrier; all 4 waves expand 4 states.

#define B 16
#define W 2048
#define T_ITERS 1024
#define HIST (T_ITERS + 1)
#define LANES 64
#define K_STEPS 16
#define RBLKS (T_ITERS / K_STEPS)      // 64 chunks
#define ROW_I4 (W / 4)                 // 512 int4 per state row

typedef unsigned long long u64;
typedef int v4i __attribute__((ext_vector_type(4)));

__device__ __forceinline__ v4i nib4(unsigned nib) {
    v4i f;
    f.x = (int)(nib & 1u);
    f.y = (int)((nib >> 1) & 1u);
    f.z = (int)((nib >> 2) & 1u);
    f.w = (int)((nib >> 3) & 1u);
    return f;
}

__global__ __launch_bounds__(256) void ca_redundant(const float* __restrict__ x,
                                                    v4i* __restrict__ out) {
    __shared__ unsigned st[K_STEPS][LANES];   // chunk's 16 packed states
    __shared__ unsigned st0[LANES];           // packed t=0 (r==0 only)

    const int blk = blockIdx.x;
    const int b = blk & (B - 1);              // row
    const int r = blk >> 4;                   // time-chunk 0..63
    const int tid = threadIdx.x;
    const int wave = tid >> 6;                // 0..3
    const int l = tid & 63;                   // lane

    if (wave == 0) {
        // ---- pack 32 thresholded floats into a u32 (bit i = cell 32l+i) ----
        const float4* xv = (const float4*)(x + (size_t)b * W + (size_t)l * 32);
        unsigned m = 0;
        #pragma unroll
        for (int i = 0; i < 8; ++i) {
            float4 v = xv[i];
            unsigned n = (v.x >= 0.5f ? 1u : 0u) | (v.y >= 0.5f ? 2u : 0u) |
                         (v.z >= 0.5f ? 4u : 0u) | (v.w >= 0.5f ? 8u : 0u);
            m |= n << (4 * i);
        }
        if (r == 0) st0[l] = m;

        // ---- chain: r+1 exchange groups of 16 steps; save only group r ----
        for (int g = 0; g <= r; ++g) {
            unsigned left  = __shfl(m, (l + LANES - 1) & (LANES - 1));
            unsigned right = __shfl(m, (l + 1) & (LANES - 1));
            // window bit p = cell (32l - 16 + p); bits [16..47] = own cells
            u64 win = ((u64)(left >> 16)) | ((u64)m << 16) | ((u64)right << 48);
            if (g < r) {
                #pragma unroll
                for (int j = 0; j < K_STEPS; ++j)
                    win = (win >> 1) ^ (win | (win << 1));   // rule 30, 64 bits
                m = (unsigned)(win >> 16);                   // valid at 16 steps
            } else {
                #pragma unroll
                for (int j = 0; j < K_STEPS; ++j) {
                    win = (win >> 1) ^ (win | (win << 1));
                    m = (unsigned)(win >> 16);               // valid for j<=15
                    st[j][l] = m;                            // 2 lanes/bank: free
                }
            }
        }
    }
    __syncthreads();

    // ---- expand: all 4 waves, 4 states each, in 2 reg-staged batches ----
    // Batch = 2 adjacent states (rows t=j, j+1 are contiguous in memory):
    // 16 ds_read_b32 -> expand into 64 data VGPRs -> 16 back-to-back
    // dwordx4 stores (16KB contiguous per wave, no interleaved work).
    // nibble c of a packed row: word c>>3 = (l>>3)+8i, shift (l&7)*4.
    if (r == 0) {
        // t = 0 row: 512 int4 split across all 256 threads (2 each)
        v4i* o = out + ((size_t)b * HIST) * ROW_I4;
        #pragma unroll
        for (int h = 0; h < 2; ++h) {
            int c = tid + 256 * h;
            unsigned u = st0[c >> 3];
            v4i f = nib4((u >> ((c & 7) * 4)) & 0xFu);
            o[c] = f;
        }
    }
    #pragma unroll
    for (int half = 0; half < 2; ++half) {
        const int j0 = wave * 4 + half * 2;    // first of 2 adjacent states
        // stage: read + expand both rows fully into registers
        v4i reg[2][8];
        #pragma unroll
        for (int s = 0; s < 2; ++s) {
            #pragma unroll
            for (int i = 0; i < 8; ++i) {
                unsigned u = st[j0 + s][(l >> 3) + 8 * i];
                reg[s][i] = nib4((u >> ((l & 7) * 4)) & 0xFu);
            }
        }
        // burst: 16 back-to-back wave-stores, 16KB contiguous
        v4i* o = out + ((size_t)b * HIST + (size_t)(r * K_STEPS + 1 + j0)) * ROW_I4;
        #pragma unroll
        for (int s = 0; s < 2; ++s) {
            #pragma unroll
            for (int i = 0; i < 8; ++i)
                o[s * ROW_I4 + l + 64 * i] = reg[s][i];
        }
    }
}

extern "C" void kernel_launch(void* const* d_in, const int* in_sizes, int n_in,
                              void* d_out, int out_size, void* d_ws, size_t ws_size,
                              hipStream_t stream) {
    const float* x = (const float*)d_in[0];
    // 1024 independent blocks (4 waves each); no workspace needed.
    ca_redundant<<<B * RBLKS, 256, 0, stream>>>(x, (v4i*)d_out);
}